// Round 2
// baseline (172.628 us; speedup 1.0000x reference)
//
#include <hip/hip_runtime.h>
#include <hip/hip_bf16.h>

// GAT encoder, N=4096, D=128, H=8.
// Pipeline: k_pack (adj->bitmask, transposed [word][row])
//           k_prep (W->Wt f16 transposed, W1->W1t f16 transposed)
//           k_wh   (Wh = nodes@W per head -> Whbt f16 [h][d][n]; f1,f2 (x log2e))
//           k_m2   (per-head global max of f2L)
//           k_attn (fused masked-softmax + PV, j-split x2, partials to ws)
//           k_comb (combine partials, /den, elu -> hcat f16 [n][h*128+d])
//           k_out  (cat@W1 + b1, elu, +nodes residual, LayerNorm -> out f32)
// ws usage ~53.5 MB, all regions fully rewritten every launch (poison-safe).

#define NN 4096
#define ALPHA 0.2f
#define EPSLN 1e-5f
#define LOG2E 1.4426950408889634f

typedef __attribute__((ext_vector_type(8))) _Float16 f16x8;
typedef __attribute__((ext_vector_type(4))) _Float16 f16x4;
typedef __attribute__((ext_vector_type(2))) _Float16 f16x2;
typedef __attribute__((ext_vector_type(4))) float f32x4;

union F16x8 { f16x8 v; f16x2 h[4]; };

// cvt_pkrtz returns __fp16x2; bit-cast to _Float16x2
static __device__ inline f16x2 pkrtz(float a, float b) {
  union { decltype(__builtin_amdgcn_cvt_pkrtz(0.f, 0.f)) r; f16x2 h; } u;
  u.r = __builtin_amdgcn_cvt_pkrtz(a, b);
  return u.h;
}

#if __has_builtin(__builtin_amdgcn_exp2f)
#define EXP2(x) __builtin_amdgcn_exp2f(x)
#else
#define EXP2(x) exp2f(x)
#endif

// ---------------- k_pack: adj int32 [4096][4096] -> maskT u64 [64 words][4096 rows]
__global__ void k_pack(const int* __restrict__ adj, unsigned long long* __restrict__ maskT) {
  int wv = threadIdx.x >> 6, l = threadIdx.x & 63;
#pragma unroll
  for (int it = 0; it < 4; ++it) {
    int wid = blockIdx.x * 16 + it * 4 + wv;      // word id = row*64 + w
    int row = wid >> 6, w = wid & 63;
    int v = adj[(size_t)row * NN + w * 64 + l];
    unsigned long long bal = __ballot(v > 0);
    if (l == 0) maskT[(size_t)w * NN + row] = bal;
  }
}

// ---------------- k_prep: Wt[h][e][d] = W[h][d][e] (f16); W1t[d][k] = W1[k][d] (f16)
__global__ void k_prep(const float* __restrict__ W, const float* __restrict__ W1,
                       _Float16* __restrict__ Wt, _Float16* __restrict__ W1t) {
  int idx = blockIdx.x * 256 + threadIdx.x;
  if (idx < 131072) {
    int h = idx >> 14, r = idx & 16383, d = r >> 7, e = r & 127;
    Wt[h * 16384 + e * 128 + d] = (_Float16)W[idx];
  } else {
    int j = idx - 131072;
    int k = j >> 7, d = j & 127;
    W1t[d * 1024 + k] = (_Float16)W1[j];
  }
}

// ---------------- k_wh: per head GEMM [4096x128]@[128x128] + f1/f2 dots
__global__ __launch_bounds__(256) void k_wh(const float* __restrict__ nodes,
    const _Float16* __restrict__ Wt, const float* __restrict__ a1,
    const float* __restrict__ a2, _Float16* __restrict__ Whbt,
    float* __restrict__ f1L, float* __restrict__ f2L) {
  int h = blockIdx.y;
  int wv = threadIdx.x >> 6, l = threadIdx.x & 63;
  int lr = l & 15, lg = l >> 4;
  int ibase = blockIdx.x * 64 + wv * 16;
  f32x4 acc[8] = {};
  const float* arow = nodes + (size_t)(ibase + lr) * 128;
  const _Float16* bbase = Wt + h * 16384;
#pragma unroll
  for (int ks = 0; ks < 4; ++ks) {
    int k0 = ks * 32 + lg * 8;
    f32x4 av0 = *(const f32x4*)(arow + k0);
    f32x4 av1 = *(const f32x4*)(arow + k0 + 4);
    F16x8 A;
    A.h[0] = pkrtz(av0[0], av0[1]);
    A.h[1] = pkrtz(av0[2], av0[3]);
    A.h[2] = pkrtz(av1[0], av1[1]);
    A.h[3] = pkrtz(av1[2], av1[3]);
#pragma unroll
    for (int nt = 0; nt < 8; ++nt) {
      f16x8 B = *(const f16x8*)(bbase + (nt * 16 + lr) * 128 + k0);
      acc[nt] = __builtin_amdgcn_mfma_f32_16x16x32_f16(A.v, B, acc[nt], 0, 0, 0);
    }
  }
  // store Wh transposed: Whbt[h][e][i]
#pragma unroll
  for (int nt = 0; nt < 8; ++nt)
#pragma unroll
    for (int r = 0; r < 4; ++r) {
      int i = ibase + lg * 4 + r;
      Whbt[(size_t)(h * 128 + nt * 16 + lr) * NN + i] = (_Float16)acc[nt][r];
    }
  // f1/f2 (pre-multiplied by log2e)
  float a1r[8], a2r[8];
#pragma unroll
  for (int nt = 0; nt < 8; ++nt) {
    a1r[nt] = a1[h * 128 + nt * 16 + lr];
    a2r[nt] = a2[h * 128 + nt * 16 + lr];
  }
#pragma unroll
  for (int r = 0; r < 4; ++r) {
    float s1 = 0.f, s2 = 0.f;
#pragma unroll
    for (int nt = 0; nt < 8; ++nt) { s1 += acc[nt][r] * a1r[nt]; s2 += acc[nt][r] * a2r[nt]; }
    s1 += __shfl_xor(s1, 1, 16); s1 += __shfl_xor(s1, 2, 16);
    s1 += __shfl_xor(s1, 4, 16); s1 += __shfl_xor(s1, 8, 16);
    s2 += __shfl_xor(s2, 1, 16); s2 += __shfl_xor(s2, 2, 16);
    s2 += __shfl_xor(s2, 4, 16); s2 += __shfl_xor(s2, 8, 16);
    if (lr == 0) {
      int i = ibase + lg * 4 + r;
      f1L[h * NN + i] = s1 * LOG2E;
      f2L[h * NN + i] = s2 * LOG2E;
    }
  }
}

// ---------------- k_m2: per-head max of f2L
__global__ void k_m2(const float* __restrict__ f2L, float* __restrict__ M2L) {
  __shared__ float red[4];
  int h = blockIdx.x, t = threadIdx.x;
  float v = -1e30f;
  for (int k = t; k < NN; k += 256) v = fmaxf(v, f2L[h * NN + k]);
#pragma unroll
  for (int off = 1; off < 64; off <<= 1) v = fmaxf(v, __shfl_xor(v, off, 64));
  if ((t & 63) == 0) red[t >> 6] = v;
  __syncthreads();
  if (t == 0) M2L[h] = fmaxf(fmaxf(red[0], red[1]), fmaxf(red[2], red[3]));
}

// ---------------- k_attn: fused masked softmax + PV. grid (32 rowtiles, 8 heads, 2 jsplit)
// block: 256 thr = 4 waves, wave = 32 rows x 128 d. ctile = 128 j. Single-pass softmax
// with m_i = lrelu(f1_i + max_j f2_j) (upper bound on row max -> exponent <= 0).
__global__ __launch_bounds__(256, 2) void k_attn(const _Float16* __restrict__ Whbt,
    const float* __restrict__ f1L, const float* __restrict__ f2L,
    const float* __restrict__ M2L, const unsigned long long* __restrict__ maskT,
    float* __restrict__ accP, float* __restrict__ denP) {
  __shared__ __align__(16) _Float16 Bt[128 * 128];  // 32 KB, rows=d (256B), XOR-swizzled
  __shared__ __align__(16) float f2s[128];
  int t = threadIdx.x, wv = t >> 6, l = t & 63, lr = l & 15, lg = l >> 4;
  int rb = blockIdx.x, h = blockIdx.y, z = blockIdx.z;
  int rowbase = rb * 128 + wv * 32;
  int r0 = rowbase + lr, r1 = r0 + 16;
  float f10 = f1L[h * NN + r0], f11 = f1L[h * NN + r1];
  float M2 = M2L[h];
  float mL0 = fmaxf(f10 + M2, ALPHA * (f10 + M2));
  float mL1 = fmaxf(f11 + M2, ALPHA * (f11 + M2));
  f32x4 acc[2][8] = {};
  float den0 = 0.f, den1 = 0.f;
  int sd = t >> 4, sc = t & 15;  // staging: row-within-pass, 16B chunk

  for (int ct = 0; ct < 16; ++ct) {
    int jt = z * 2048 + ct * 128;
    __syncthreads();  // prev-iter reads done before overwrite
    // stage B tile: Whbt[h][d][jt..jt+128) -> Bt[d][128] f16, source pre-swizzled
    f16x8 stg[8];
#pragma unroll
    for (int pass = 0; pass < 8; ++pass) {
      int d = pass * 16 + sd;
      stg[pass] = *(const f16x8*)(Whbt + ((size_t)(h * 128 + d) << 12) + jt + ((sc ^ (d & 15)) << 3));
    }
#pragma unroll
    for (int pass = 0; pass < 8; ++pass)
      *(f16x8*)((char*)Bt + pass * 4096 + t * 16) = stg[pass];
    if (t < 128) f2s[t] = f2L[h * NN + jt + t];
    // mask words for this ctile (2 u64 per row)
    int w0 = jt >> 6;
    unsigned long long m00 = maskT[(size_t)w0 * NN + r0];
    unsigned long long m01 = maskT[(size_t)(w0 + 1) * NN + r0];
    unsigned long long m10 = maskT[(size_t)w0 * NN + r1];
    unsigned long long m11 = maskT[(size_t)(w0 + 1) * NN + r1];
    __syncthreads();

#pragma unroll
    for (int ks = 0; ks < 4; ++ks) {
      int jb = ks * 32 + lg * 8;                 // lane's j base within ctile
      f32x4 f2a = *(const f32x4*)&f2s[jb];
      f32x4 f2b = *(const f32x4*)&f2s[jb + 4];
      unsigned long long w0sel = (ks < 2) ? m00 : m01;   // compile-time per ks
      unsigned long long w1sel = (ks < 2) ? m10 : m11;
      int sh = (ks & 1) * 32 + lg * 8;
      unsigned bits0 = (unsigned)(w0sel >> sh);
      unsigned bits1 = (unsigned)(w1sel >> sh);
      float p0[8], p1[8];
#pragma unroll
      for (int e = 0; e < 8; ++e) {
        float f2v = (e < 4) ? f2a[e] : f2b[e - 4];
        float t0 = f10 + f2v;                    // log2e pre-folded
        float u0 = fmaxf(t0, ALPHA * t0) - mL0;
        u0 = ((bits0 >> e) & 1) ? u0 : -16384.f;
        p0[e] = EXP2(u0);
        den0 += p0[e];
        float t1 = f11 + f2v;
        float u1 = fmaxf(t1, ALPHA * t1) - mL1;
        u1 = ((bits1 >> e) & 1) ? u1 : -16384.f;
        p1[e] = EXP2(u1);
        den1 += p1[e];
      }
      F16x8 A0, A1;
#pragma unroll
      for (int q = 0; q < 4; ++q) {
        A0.h[q] = pkrtz(p0[2 * q], p0[2 * q + 1]);
        A1.h[q] = pkrtz(p1[2 * q], p1[2 * q + 1]);
      }
#pragma unroll
      for (int nt = 0; nt < 8; ++nt) {
        int d = nt * 16 + lr;
        int byteoff = d * 256 + ((jb * 2) ^ ((d & 15) << 4));
        f16x8 B = *(const f16x8*)((const char*)Bt + byteoff);
        acc[0][nt] = __builtin_amdgcn_mfma_f32_16x16x32_f16(A0.v, B, acc[0][nt], 0, 0, 0);
        acc[1][nt] = __builtin_amdgcn_mfma_f32_16x16x32_f16(A1.v, B, acc[1][nt], 0, 0, 0);
      }
    }
  }
  // reduce denom across the 4 lanes sharing a row (lg groups)
  den0 += __shfl_xor(den0, 16, 64); den0 += __shfl_xor(den0, 32, 64);
  den1 += __shfl_xor(den1, 16, 64); den1 += __shfl_xor(den1, 32, 64);
  size_t zb = ((size_t)z * 8 + h) * NN;
  if (l < 16) { denP[zb + r0] = den0; denP[zb + r1] = den1; }
#pragma unroll
  for (int mt = 0; mt < 2; ++mt)
#pragma unroll
    for (int nt = 0; nt < 8; ++nt)
#pragma unroll
      for (int r = 0; r < 4; ++r) {
        int i = rowbase + mt * 16 + lg * 4 + r;
        accP[(zb + i) * 128 + nt * 16 + lr] = acc[mt][nt][r];
      }
}

// ---------------- k_comb: combine jsplit partials, /den, elu -> hcat f16 [n][h*128+d]
__global__ void k_comb(const float* __restrict__ accP, const float* __restrict__ denP,
                       _Float16* __restrict__ hcat) {
  int i = blockIdx.x, t = threadIdx.x;
  int h = t >> 5, dd = (t & 31) * 4;
  size_t i0 = ((size_t)h * NN + i) * 128 + dd;
  size_t i1 = ((size_t)(8 + h) * NN + i) * 128 + dd;
  f32x4 a = *(const f32x4*)(accP + i0);
  f32x4 b = *(const f32x4*)(accP + i1);
  float den = denP[h * NN + i] + denP[(8 + h) * NN + i];
  float rc = __builtin_amdgcn_rcpf(den);
  f16x4 o;
#pragma unroll
  for (int q = 0; q < 4; ++q) {
    float x = (a[q] + b[q]) * rc;
    x = x > 0.f ? x : EXP2(x * LOG2E) - 1.f;
    o[q] = (_Float16)x;
  }
  *(f16x4*)(hcat + (size_t)i * 1024 + t * 4) = o;
}

// ---------------- k_out: x = elu(cat@W1 + b1); out = LN(nodes + x)
__global__ __launch_bounds__(128) void k_out(const _Float16* __restrict__ hcat,
    const _Float16* __restrict__ W1t, const float* __restrict__ b1,
    const float* __restrict__ nodes, const float* __restrict__ gamma,
    const float* __restrict__ beta, float* __restrict__ out) {
  __shared__ __align__(16) float ys[2][16][132];
  int wv = threadIdx.x >> 6, l = threadIdx.x & 63, lr = l & 15, lg = l >> 4;
  int ibase = blockIdx.x * 32 + wv * 16;
  f32x4 acc[8] = {};
  const _Float16* arow = hcat + (size_t)(ibase + lr) * 1024;
#pragma unroll 4
  for (int ks = 0; ks < 32; ++ks) {
    int k0 = ks * 32 + lg * 8;
    f16x8 A = *(const f16x8*)(arow + k0);
#pragma unroll
    for (int nt = 0; nt < 8; ++nt) {
      f16x8 B = *(const f16x8*)(W1t + (nt * 16 + lr) * 1024 + k0);
      acc[nt] = __builtin_amdgcn_mfma_f32_16x16x32_f16(A, B, acc[nt], 0, 0, 0);
    }
  }
#pragma unroll
  for (int nt = 0; nt < 8; ++nt) {
    float bv = b1[nt * 16 + lr];
#pragma unroll
    for (int r = 0; r < 4; ++r) {
      int i = ibase + lg * 4 + r;
      float x = acc[nt][r] + bv;
      x = x > 0.f ? x : EXP2(x * LOG2E) - 1.f;
      ys[wv][lg * 4 + r][nt * 16 + lr] = x + nodes[(size_t)i * 128 + nt * 16 + lr];
    }
  }
  __syncthreads();
  int row = l >> 2, seg = l & 3;   // 4 lanes per row, 32 f32 each
  float sum = 0.f, sq = 0.f;
  f32x4 vbuf[8];
#pragma unroll
  for (int q = 0; q < 8; ++q) {
    f32x4 v = *(const f32x4*)&ys[wv][row][seg * 32 + q * 4];
    vbuf[q] = v;
    sum += v[0] + v[1] + v[2] + v[3];
    sq += v[0] * v[0] + v[1] * v[1] + v[2] * v[2] + v[3] * v[3];
  }
  sum += __shfl_xor(sum, 1, 4); sum += __shfl_xor(sum, 2, 4);
  sq += __shfl_xor(sq, 1, 4); sq += __shfl_xor(sq, 2, 4);
  float mu = sum * (1.f / 128.f);
  float var = sq * (1.f / 128.f) - mu * mu;
  float rs = __builtin_amdgcn_rsqf(var + EPSLN);
  int i = ibase + row;
#pragma unroll
  for (int q = 0; q < 8; ++q) {
    int d = seg * 32 + q * 4;
    f32x4 g = *(const f32x4*)(gamma + d);
    f32x4 bb = *(const f32x4*)(beta + d);
    f32x4 o;
#pragma unroll
    for (int c = 0; c < 4; ++c) o[c] = (vbuf[q][c] - mu) * rs * g[c] + bb[c];
    *(f32x4*)(out + (size_t)i * 128 + d) = o;
  }
}

extern "C" void kernel_launch(void* const* d_in, const int* in_sizes, int n_in,
                              void* d_out, int out_size, void* d_ws, size_t ws_size,
                              hipStream_t stream) {
  const float* nodes = (const float*)d_in[0];
  const int* adj = (const int*)d_in[1];
  const float* W = (const float*)d_in[2];
  const float* a1 = (const float*)d_in[3];
  const float* a2 = (const float*)d_in[4];
  const float* W1 = (const float*)d_in[5];
  const float* b1 = (const float*)d_in[6];
  const float* gamma = (const float*)d_in[7];
  const float* beta = (const float*)d_in[8];
  float* out = (float*)d_out;
  char* ws = (char*)d_ws;

  // ws layout (bytes), total ~53.5 MB
  const size_t OFF_MASK = 0;                       // 2 MB
  const size_t OFF_WHBT = 2097152;                 // 8.4 MB
  const size_t OFF_F1 = OFF_WHBT + 8388608;        // 128 KB
  const size_t OFF_F2 = OFF_F1 + 131072;           // 128 KB
  const size_t OFF_M2 = OFF_F2 + 131072;           // 256 B
  const size_t OFF_WT = OFF_M2 + 256;              // 256 KB
  const size_t OFF_W1T = OFF_WT + 262144;          // 256 KB
  const size_t OFF_ACC = OFF_W1T + 262144;         // 33.55 MB
  const size_t OFF_DEN = OFF_ACC + 33554432;       // 256 KB
  const size_t OFF_HCAT = OFF_DEN + 262144;        // 8.4 MB

  unsigned long long* maskT = (unsigned long long*)(ws + OFF_MASK);
  _Float16* Whbt = (_Float16*)(ws + OFF_WHBT);
  float* f1L = (float*)(ws + OFF_F1);
  float* f2L = (float*)(ws + OFF_F2);
  float* M2L = (float*)(ws + OFF_M2);
  _Float16* Wt = (_Float16*)(ws + OFF_WT);
  _Float16* W1t = (_Float16*)(ws + OFF_W1T);
  float* accP = (float*)(ws + OFF_ACC);
  float* denP = (float*)(ws + OFF_DEN);
  _Float16* hcat = (_Float16*)(ws + OFF_HCAT);

  k_pack<<<16384, 256, 0, stream>>>(adj, maskT);
  k_prep<<<1024, 256, 0, stream>>>(W, W1, Wt, W1t);
  k_wh<<<dim3(64, 8), 256, 0, stream>>>(nodes, Wt, a1, a2, Whbt, f1L, f2L);
  k_m2<<<8, 256, 0, stream>>>(f2L, M2L);
  k_attn<<<dim3(32, 8, 2), 256, 0, stream>>>(Whbt, f1L, f2L, M2L, maskT, accP, denP);
  k_comb<<<4096, 256, 0, stream>>>(accP, denP, hcat);
  k_out<<<128, 128, 0, stream>>>(hcat, W1t, b1, nodes, gamma, beta, out);
}

// Round 3
// 165.233 us; speedup vs baseline: 1.0448x; 1.0448x over previous
//
#include <hip/hip_runtime.h>
#include <hip/hip_bf16.h>

// GAT encoder, N=4096, D=128, H=8.
// k_pack (adj->bitmask, transposed [word][row], int4 loads + ballot spread)
// k_prep (W->Wt f16 transposed, W1->W1t f16 transposed)
// k_wh   (Wh = nodes@W per head -> Whbt f16 [h][d][n]; f1,f2 (x log2e))
// k_m2   (per-head global max of f2L)
// k_attn (fused masked-softmax + PV, full-j per block, dbuf LDS, epilogue
//         /den + elu -> hcat f16 [n][h*128+d])
// k_out  (cat@W1 + b1, elu, +nodes residual, LayerNorm -> out f32)
// ws ~19.7 MB, all regions fully rewritten every launch (poison-safe).

#define NN 4096
#define ALPHA 0.2f
#define EPSLN 1e-5f
#define LOG2E 1.4426950408889634f

typedef __attribute__((ext_vector_type(8))) _Float16 f16x8;
typedef __attribute__((ext_vector_type(4))) _Float16 f16x4;
typedef __attribute__((ext_vector_type(2))) _Float16 f16x2;
typedef __attribute__((ext_vector_type(4))) float f32x4;
typedef __attribute__((ext_vector_type(4))) int i32x4;

union F16x8 { f16x8 v; f16x2 h[4]; };

static __device__ inline f16x2 pkrtz(float a, float b) {
  union { decltype(__builtin_amdgcn_cvt_pkrtz(0.f, 0.f)) r; f16x2 h; } u;
  u.r = __builtin_amdgcn_cvt_pkrtz(a, b);
  return u.h;
}

#if __has_builtin(__builtin_amdgcn_exp2f)
#define EXP2(x) __builtin_amdgcn_exp2f(x)
#else
#define EXP2(x) exp2f(x)
#endif

// spread 16 bits to positions 4k
static __device__ inline unsigned long long sp4(unsigned long long x) {
  x = (x | (x << 24)) & 0x000000FF000000FFULL;
  x = (x | (x << 12)) & 0x000F000F000F000FULL;
  x = (x | (x << 6))  & 0x0303030303030303ULL;
  x = (x | (x << 3))  & 0x1111111111111111ULL;
  return x;
}

// ---------------- k_pack: adj int32 [4096][4096] -> maskT u64 [64 words][4096 rows]
// wave covers 256 consecutive columns of one row via int4 loads (16B/lane).
__global__ void k_pack(const int* __restrict__ adj, unsigned long long* __restrict__ maskT) {
  int wv = threadIdx.x >> 6, l = threadIdx.x & 63;
  int gid = blockIdx.x * 4 + wv;           // 0..65535
  int row = gid >> 4, chunk = gid & 15;    // chunk of 256 cols
  i32x4 v = *(const i32x4*)(adj + ((size_t)row << 12) + chunk * 256 + l * 4);
  unsigned long long b0 = __ballot(v.x > 0);
  unsigned long long b1 = __ballot(v.y > 0);
  unsigned long long b2 = __ballot(v.z > 0);
  unsigned long long b3 = __ballot(v.w > 0);
  if (l < 4) {
    int sh = l * 16;
    unsigned long long w = sp4((b0 >> sh) & 0xFFFF)
                         | (sp4((b1 >> sh) & 0xFFFF) << 1)
                         | (sp4((b2 >> sh) & 0xFFFF) << 2)
                         | (sp4((b3 >> sh) & 0xFFFF) << 3);
    maskT[(size_t)(chunk * 4 + l) * NN + row] = w;
  }
}

// ---------------- k_prep: Wt[h][e][d] = W[h][d][e] (f16); W1t[d][k] = W1[k][d] (f16)
__global__ void k_prep(const float* __restrict__ W, const float* __restrict__ W1,
                       _Float16* __restrict__ Wt, _Float16* __restrict__ W1t) {
  int idx = blockIdx.x * 256 + threadIdx.x;
  if (idx < 131072) {
    int h = idx >> 14, r = idx & 16383, d = r >> 7, e = r & 127;
    Wt[h * 16384 + e * 128 + d] = (_Float16)W[idx];
  } else {
    int j = idx - 131072;
    int k = j >> 7, d = j & 127;
    W1t[d * 1024 + k] = (_Float16)W1[j];
  }
}

// ---------------- k_wh: per head GEMM [4096x128]@[128x128] + f1/f2 dots
__global__ __launch_bounds__(256) void k_wh(const float* __restrict__ nodes,
    const _Float16* __restrict__ Wt, const float* __restrict__ a1,
    const float* __restrict__ a2, _Float16* __restrict__ Whbt,
    float* __restrict__ f1L, float* __restrict__ f2L) {
  int h = blockIdx.y;
  int wv = threadIdx.x >> 6, l = threadIdx.x & 63;
  int lr = l & 15, lg = l >> 4;
  int ibase = blockIdx.x * 64 + wv * 16;
  f32x4 acc[8] = {};
  const float* arow = nodes + (size_t)(ibase + lr) * 128;
  const _Float16* bbase = Wt + h * 16384;
#pragma unroll
  for (int ks = 0; ks < 4; ++ks) {
    int k0 = ks * 32 + lg * 8;
    f32x4 av0 = *(const f32x4*)(arow + k0);
    f32x4 av1 = *(const f32x4*)(arow + k0 + 4);
    F16x8 A;
    A.h[0] = pkrtz(av0[0], av0[1]);
    A.h[1] = pkrtz(av0[2], av0[3]);
    A.h[2] = pkrtz(av1[0], av1[1]);
    A.h[3] = pkrtz(av1[2], av1[3]);
#pragma unroll
    for (int nt = 0; nt < 8; ++nt) {
      f16x8 B = *(const f16x8*)(bbase + (nt * 16 + lr) * 128 + k0);
      acc[nt] = __builtin_amdgcn_mfma_f32_16x16x32_f16(A.v, B, acc[nt], 0, 0, 0);
    }
  }
#pragma unroll
  for (int nt = 0; nt < 8; ++nt)
#pragma unroll
    for (int r = 0; r < 4; ++r) {
      int i = ibase + lg * 4 + r;
      Whbt[(size_t)(h * 128 + nt * 16 + lr) * NN + i] = (_Float16)acc[nt][r];
    }
  float a1r[8], a2r[8];
#pragma unroll
  for (int nt = 0; nt < 8; ++nt) {
    a1r[nt] = a1[h * 128 + nt * 16 + lr];
    a2r[nt] = a2[h * 128 + nt * 16 + lr];
  }
#pragma unroll
  for (int r = 0; r < 4; ++r) {
    float s1 = 0.f, s2 = 0.f;
#pragma unroll
    for (int nt = 0; nt < 8; ++nt) { s1 += acc[nt][r] * a1r[nt]; s2 += acc[nt][r] * a2r[nt]; }
    s1 += __shfl_xor(s1, 1, 16); s1 += __shfl_xor(s1, 2, 16);
    s1 += __shfl_xor(s1, 4, 16); s1 += __shfl_xor(s1, 8, 16);
    s2 += __shfl_xor(s2, 1, 16); s2 += __shfl_xor(s2, 2, 16);
    s2 += __shfl_xor(s2, 4, 16); s2 += __shfl_xor(s2, 8, 16);
    if (lr == 0) {
      int i = ibase + lg * 4 + r;
      f1L[h * NN + i] = s1 * LOG2E;
      f2L[h * NN + i] = s2 * LOG2E;
    }
  }
}

// ---------------- k_m2: per-head max of f2L
__global__ void k_m2(const float* __restrict__ f2L, float* __restrict__ M2L) {
  __shared__ float red[4];
  int h = blockIdx.x, t = threadIdx.x;
  float v = -1e30f;
  for (int k = t; k < NN; k += 256) v = fmaxf(v, f2L[h * NN + k]);
#pragma unroll
  for (int off = 1; off < 64; off <<= 1) v = fmaxf(v, __shfl_xor(v, off, 64));
  if ((t & 63) == 0) red[t >> 6] = v;
  __syncthreads();
  if (t == 0) M2L[h] = fmaxf(fmaxf(red[0], red[1]), fmaxf(red[2], red[3]));
}

// ---------------- k_attn: fused masked softmax + PV, full j-range per block.
// grid (64 rowtiles, 8 heads), 256 thr = 4 waves, wave = 16 rows x 128 d.
// ctile = 128 j, double-buffered Bt, ONE barrier per tile, reg-staged loads.
// Single-pass softmax: m_i = lrelu(f1_i + max_j f2_j) upper-bounds row max.
// Epilogue: /den + elu -> hcat f16 [n][h*128+d].
__global__ __launch_bounds__(256, 2) void k_attn(const _Float16* __restrict__ Whbt,
    const float* __restrict__ f1L, const float* __restrict__ f2L,
    const float* __restrict__ M2L, const unsigned long long* __restrict__ maskT,
    _Float16* __restrict__ hcat) {
  __shared__ __align__(16) _Float16 Bt[2][128 * 128];  // 2 x 32 KB, XOR-swizzled
  __shared__ __align__(16) float f2s[2][128];
  int t = threadIdx.x, wv = t >> 6, l = t & 63, lr = l & 15, lg = l >> 4;
  int rb = blockIdx.x, h = blockIdx.y;
  int rowbase = rb * 64 + wv * 16;
  int r0 = rowbase + lr;
  float f10 = f1L[h * NN + r0];
  float M2 = M2L[h];
  float tM = f10 + M2;
  float mL = fmaxf(tM, ALPHA * tM);
  float f1m = f10 - mL;               // u = max(f1m + f2, fma(a, f2, af1))
  float af1 = ALPHA * f10 - mL;
  f32x4 acc[8] = {};
  float den = 0.f;
  int sd = t >> 4, sc = t & 15;
  const _Float16* src = Whbt + ((size_t)h << 19);
  const float* f2p = f2L + h * NN;

  // prologue: stage tile 0 into regs
  f16x8 stg[8];
  float f2r;
  unsigned long long m0n, m1n;
#pragma unroll
  for (int pass = 0; pass < 8; ++pass) {
    int d = pass * 16 + sd;
    stg[pass] = *(const f16x8*)(src + ((size_t)d << 12) + ((sc ^ sd) << 3));
  }
  f2r = f2p[t & 127];
  m0n = maskT[(size_t)0 * NN + r0];
  m1n = maskT[(size_t)1 * NN + r0];

  for (int ct = 0; ct < 32; ++ct) {
    char* btw = (char*)Bt + (ct & 1) * 32768;
    // write phase: regs -> LDS buffer (ct&1)
#pragma unroll
    for (int pass = 0; pass < 8; ++pass)
      *(f16x8*)(btw + pass * 4096 + t * 16) = stg[pass];
    if (t < 128) f2s[ct & 1][t] = f2r;
    unsigned long long m0 = m0n, m1 = m1n;
    // issue next tile's global loads (consumed next iteration)
    if (ct + 1 < 32) {
      int jt = (ct + 1) * 128;
#pragma unroll
      for (int pass = 0; pass < 8; ++pass) {
        int d = pass * 16 + sd;
        stg[pass] = *(const f16x8*)(src + ((size_t)d << 12) + jt + ((sc ^ sd) << 3));
      }
      f2r = f2p[jt + (t & 127)];
      m0n = maskT[(size_t)(2 * ct + 2) * NN + r0];
      m1n = maskT[(size_t)(2 * ct + 3) * NN + r0];
    }
    __syncthreads();
    const char* btr = btw;
    const float* f2c = f2s[ct & 1];
#pragma unroll
    for (int ks = 0; ks < 4; ++ks) {
      int jb = ks * 32 + lg * 8;
      f32x4 f2a = *(const f32x4*)(f2c + jb);
      f32x4 f2b = *(const f32x4*)(f2c + jb + 4);
      unsigned bits = (unsigned)(((ks < 2) ? m0 : m1) >> ((ks & 1) * 32 + lg * 8));
      float p[8];
#pragma unroll
      for (int e = 0; e < 8; ++e) {
        float f2v = (e < 4) ? f2a[e] : f2b[e - 4];
        float u = fmaxf(f1m + f2v, fmaf(ALPHA, f2v, af1));
        u = ((bits >> e) & 1) ? u : -16384.f;
        p[e] = EXP2(u);
        den += p[e];
      }
      F16x8 A;
#pragma unroll
      for (int q = 0; q < 4; ++q) A.h[q] = pkrtz(p[2 * q], p[2 * q + 1]);
#pragma unroll
      for (int nt = 0; nt < 8; ++nt) {
        int byteoff = (nt * 16 + lr) * 256 + ((jb * 2) ^ (lr << 4));
        f16x8 B = *(const f16x8*)(btr + byteoff);
        acc[nt] = __builtin_amdgcn_mfma_f32_16x16x32_f16(A.v, B, acc[nt], 0, 0, 0);
      }
    }
  }
  // den: sum the 4 j-groups (lg) per row
  den += __shfl_xor(den, 16, 64);
  den += __shfl_xor(den, 32, 64);
  // epilogue: /den, elu, store f16
#pragma unroll
  for (int r = 0; r < 4; ++r) {
    float dv = __shfl(den, lg * 4 + r, 16);
    float rc = __builtin_amdgcn_rcpf(dv);
    size_t base = (size_t)(rowbase + lg * 4 + r) * 1024 + h * 128 + lr;
#pragma unroll
    for (int nt = 0; nt < 8; ++nt) {
      float x = acc[nt][r] * rc;
      x = x > 0.f ? x : EXP2(x * LOG2E) - 1.f;
      hcat[base + nt * 16] = (_Float16)x;
    }
  }
}

// ---------------- k_out: x = elu(cat@W1 + b1); out = LN(nodes + x)
__global__ __launch_bounds__(128) void k_out(const _Float16* __restrict__ hcat,
    const _Float16* __restrict__ W1t, const float* __restrict__ b1,
    const float* __restrict__ nodes, const float* __restrict__ gamma,
    const float* __restrict__ beta, float* __restrict__ out) {
  __shared__ __align__(16) float ys[2][16][132];
  int wv = threadIdx.x >> 6, l = threadIdx.x & 63, lr = l & 15, lg = l >> 4;
  int ibase = blockIdx.x * 32 + wv * 16;
  f32x4 acc[8] = {};
  const _Float16* arow = hcat + (size_t)(ibase + lr) * 1024;
#pragma unroll 4
  for (int ks = 0; ks < 32; ++ks) {
    int k0 = ks * 32 + lg * 8;
    f16x8 A = *(const f16x8*)(arow + k0);
#pragma unroll
    for (int nt = 0; nt < 8; ++nt) {
      f16x8 B = *(const f16x8*)(W1t + (nt * 16 + lr) * 1024 + k0);
      acc[nt] = __builtin_amdgcn_mfma_f32_16x16x32_f16(A, B, acc[nt], 0, 0, 0);
    }
  }
#pragma unroll
  for (int nt = 0; nt < 8; ++nt) {
    float bv = b1[nt * 16 + lr];
#pragma unroll
    for (int r = 0; r < 4; ++r) {
      int i = ibase + lg * 4 + r;
      float x = acc[nt][r] + bv;
      x = x > 0.f ? x : EXP2(x * LOG2E) - 1.f;
      ys[wv][lg * 4 + r][nt * 16 + lr] = x + nodes[(size_t)i * 128 + nt * 16 + lr];
    }
  }
  __syncthreads();
  int row = l >> 2, seg = l & 3;
  float sum = 0.f, sq = 0.f;
  f32x4 vbuf[8];
#pragma unroll
  for (int q = 0; q < 8; ++q) {
    f32x4 v = *(const f32x4*)&ys[wv][row][seg * 32 + q * 4];
    vbuf[q] = v;
    sum += v[0] + v[1] + v[2] + v[3];
    sq += v[0] * v[0] + v[1] * v[1] + v[2] * v[2] + v[3] * v[3];
  }
  sum += __shfl_xor(sum, 1, 4); sum += __shfl_xor(sum, 2, 4);
  sq += __shfl_xor(sq, 1, 4); sq += __shfl_xor(sq, 2, 4);
  float mu = sum * (1.f / 128.f);
  float var = sq * (1.f / 128.f) - mu * mu;
  float rs = __builtin_amdgcn_rsqf(var + EPSLN);
  int i = ibase + row;
#pragma unroll
  for (int q = 0; q < 8; ++q) {
    int d = seg * 32 + q * 4;
    f32x4 g = *(const f32x4*)(gamma + d);
    f32x4 bb = *(const f32x4*)(beta + d);
    f32x4 o;
#pragma unroll
    for (int c = 0; c < 4; ++c) o[c] = (vbuf[q][c] - mu) * rs * g[c] + bb[c];
    *(f32x4*)(out + (size_t)i * 128 + d) = o;
  }
}

extern "C" void kernel_launch(void* const* d_in, const int* in_sizes, int n_in,
                              void* d_out, int out_size, void* d_ws, size_t ws_size,
                              hipStream_t stream) {
  const float* nodes = (const float*)d_in[0];
  const int* adj = (const int*)d_in[1];
  const float* W = (const float*)d_in[2];
  const float* a1 = (const float*)d_in[3];
  const float* a2 = (const float*)d_in[4];
  const float* W1 = (const float*)d_in[5];
  const float* b1 = (const float*)d_in[6];
  const float* gamma = (const float*)d_in[7];
  const float* beta = (const float*)d_in[8];
  float* out = (float*)d_out;
  char* ws = (char*)d_ws;

  // ws layout (bytes), total ~19.7 MB
  const size_t OFF_MASK = 0;                       // 2 MB
  const size_t OFF_WHBT = 2097152;                 // 8.4 MB
  const size_t OFF_F1 = OFF_WHBT + 8388608;        // 128 KB
  const size_t OFF_F2 = OFF_F1 + 131072;           // 128 KB
  const size_t OFF_M2 = OFF_F2 + 131072;           // 256 B
  const size_t OFF_WT = OFF_M2 + 256;              // 256 KB
  const size_t OFF_W1T = OFF_WT + 262144;          // 256 KB
  const size_t OFF_HCAT = OFF_W1T + 262144;        // 8.4 MB

  unsigned long long* maskT = (unsigned long long*)(ws + OFF_MASK);
  _Float16* Whbt = (_Float16*)(ws + OFF_WHBT);
  float* f1L = (float*)(ws + OFF_F1);
  float* f2L = (float*)(ws + OFF_F2);
  float* M2L = (float*)(ws + OFF_M2);
  _Float16* Wt = (_Float16*)(ws + OFF_WT);
  _Float16* W1t = (_Float16*)(ws + OFF_W1T);
  _Float16* hcat = (_Float16*)(ws + OFF_HCAT);

  k_pack<<<16384, 256, 0, stream>>>(adj, maskT);
  k_prep<<<1024, 256, 0, stream>>>(W, W1, Wt, W1t);
  k_wh<<<dim3(64, 8), 256, 0, stream>>>(nodes, Wt, a1, a2, Whbt, f1L, f2L);
  k_m2<<<8, 256, 0, stream>>>(f2L, M2L);
  k_attn<<<dim3(64, 8), 256, 0, stream>>>(Whbt, f1L, f2L, M2L, maskT, hcat);
  k_out<<<128, 128, 0, stream>>>(hcat, W1t, b1, nodes, gamma, beta, out);
}